// Round 2
// baseline (233.420 us; speedup 1.0000x reference)
//
#include <hip/hip_runtime.h>
#include <math.h>

// 1D grayscale dilation (max-plus conv), K=11, halo=5, fp32.
// out[i] = max_j ( x[i-5+j] + h[j] ),  h[j] = -(j-5)^2 / (4*scale)
//
// R1: thread-contiguous coarsening breaks per-instruction coalescing.
// R2/R3: register-reuse structures get serialized by the register minimizer.
// R4 (LDS tile): 81.7us, nothing >40% busy.
// R5 (wave shuffles, no barrier): 80.5us -- IDENTICAL. Conclusion: the
//   common factor is the LDS crossbar + lgkmcnt fence between loads and
//   VALU (ds_read / ds_bpermute both stall every fmax behind lgkmcnt(0)).
// R6 (this): NO LDS pipe at all. Each quad's 5-quad window is read directly
//   from global with 5 aligned float4 loads (each a contiguous coalesced
//   1KiB wave-read; 4/5 of the lines are L1/L2 hits from the overlap).
//   Dependence chain is purely load -> vmcnt -> fmax -> store. 10 loads
//   in flight per wave (1 addr VGPR + offset: immediates each). Grid-stride
//   at 2048 blocks, VGPR ~60 -> full 8 waves/SIMD occupancy.

#define BLOCK   256
#define QPT     2                      // quads per thread per tile iteration
#define TILEQ   (BLOCK * QPT)          // 512 quads per tile
#define MAXGRID 2048                   // 8 blocks/CU, grid-stride the rest

__device__ __forceinline__ float4 dilate_quad(
    const float4* L,   // L[0..4] = quads q-2 .. q+2
    float hp1, float hp2, float hp3, float hp4, float hp5)
{
    // w[k] = x[4*q - 8 + k], k = 0..19
    float w[20];
#pragma unroll
    for (int r = 0; r < 5; ++r) {
        w[4*r+0] = L[r].x; w[4*r+1] = L[r].y;
        w[4*r+2] = L[r].z; w[4*r+3] = L[r].w;
    }
    float4 o; float* op = &o.x;
#pragma unroll
    for (int i = 0; i < 4; ++i) {      // static indices after unroll
        const int c = 8 + i;
        float m = w[c];                // hp[0] == 0
        m = fmaxf(m, hp1 + fmaxf(w[c-1], w[c+1]));
        m = fmaxf(m, hp2 + fmaxf(w[c-2], w[c+2]));
        m = fmaxf(m, hp3 + fmaxf(w[c-3], w[c+3]));
        m = fmaxf(m, hp4 + fmaxf(w[c-4], w[c+4]));
        m = fmaxf(m, hp5 + fmaxf(w[c-5], w[c+5]));
        op[i] = m;
    }
    return o;
}

__global__ __launch_bounds__(BLOCK) void dilate1d_kernel(
    const float4* __restrict__ x4,
    const float*  __restrict__ scale_p,
    float4*       __restrict__ out4,
    int n4,        // number of float4 elements in x / out
    int ntiles)    // ceil(n4 / TILEQ)
{
    const float  NEG  = -INFINITY;
    const float4 NEG4 = make_float4(NEG, NEG, NEG, NEG);

    // structuring element: hp[d] = -d^2/(4s)  (hoisted out of the loop)
    const float r4s = 1.0f / (4.0f * scale_p[0]);
    const float hp1 = -1.0f  * r4s;
    const float hp2 = -4.0f  * r4s;
    const float hp3 = -9.0f  * r4s;
    const float hp4 = -16.0f * r4s;
    const float hp5 = -25.0f * r4s;

    for (int tile = blockIdx.x; tile < ntiles; tile += gridDim.x) {
        const int t0 = tile * TILEQ;
        const int q0 = t0 + threadIdx.x;         // first quad of this thread
        const int q1 = q0 + BLOCK;               // second quad

        float4 A[5], B[5];
        const bool interior = (t0 >= 2) && (t0 + TILEQ + 2 <= n4);
        if (interior) {
            // 10 independent loads, no consumer until the fmax chain.
            // Base addr in one VGPR, r folded into offset: immediates.
            const float4* pa = x4 + (q0 - 2);
            const float4* pb = x4 + (q1 - 2);
#pragma unroll
            for (int r = 0; r < 5; ++r) A[r] = pa[r];
#pragma unroll
            for (int r = 0; r < 5; ++r) B[r] = pb[r];
        } else {
            // only the first and last tiles take this path
#pragma unroll
            for (int r = 0; r < 5; ++r) {
                int g = q0 - 2 + r;
                A[r] = (g >= 0 && g < n4) ? x4[g] : NEG4;
            }
#pragma unroll
            for (int r = 0; r < 5; ++r) {
                int g = q1 - 2 + r;
                B[r] = (g >= 0 && g < n4) ? x4[g] : NEG4;
            }
        }

        out4[q0] = dilate_quad(A, hp1, hp2, hp3, hp4, hp5);
        out4[q1] = dilate_quad(B, hp1, hp2, hp3, hp4, hp5);
    }
}

extern "C" void kernel_launch(void* const* d_in, const int* in_sizes, int n_in,
                              void* d_out, int out_size, void* d_ws, size_t ws_size,
                              hipStream_t stream) {
    const float* x       = (const float*)d_in[0];
    const float* scale_p = (const float*)d_in[1];
    float*       out     = (float*)d_out;

    int n      = in_sizes[0];
    int n4     = n / 4;                          // n = 2^25 -> n4 = 2^23
    int ntiles = (n4 + TILEQ - 1) / TILEQ;       // 16384
    int grid   = ntiles < MAXGRID ? ntiles : MAXGRID;

    dilate1d_kernel<<<grid, BLOCK, 0, stream>>>(
        (const float4*)x, scale_p, (float4*)out, n4, ntiles);
}